// Round 2
// baseline (11318.185 us; speedup 1.0000x reference)
//
#include <hip/hip_runtime.h>
#include <math.h>

#define T_STEPS 100
#define B_DIM 128
#define I_DIM 1024
#define H_DIM 4096
#define O_DIM 512
#define NCH1 8    // GEMM1 K-chunks (K=1024, chunk=128)
#define NCH2 32   // GEMM2 K-chunks (K=4096, chunk=128)

// Order-preserving float->uint map so atomicMax(uint) == float max.
__device__ __forceinline__ unsigned fmap(float f){
  unsigned u = __float_as_uint(f);
  return (u & 0x80000000u) ? ~u : (u | 0x80000000u);
}
__device__ __forceinline__ float funmap(unsigned m){
  unsigned u = (m & 0x80000000u) ? (m & 0x7FFFFFFFu) : ~m;
  return __uint_as_float(u);
}
// dyn_vth = vth * tanh(grad_win * max), vth=0.3, grad_win=0.3 (both layers)
__device__ __forceinline__ float vth_of(unsigned m){
  return 0.3f * tanhf(0.3f * funmap(m));
}

__global__ __launch_bounds__(256) void init_kernel(
    float* hv1, float* ov1, float* out,
    unsigned* hmaxA, unsigned* omaxA, unsigned* ticket)
{
  int i = blockIdx.x * 256 + threadIdx.x;
  if (i < B_DIM*H_DIM) hv1[i] = 0.f;
  if (i < B_DIM*O_DIM) { ov1[i] = 0.f; out[i] = 0.f; }
  if (i < 256) ticket[i] = 0u;
  if (i < 128) {
    // slot 0 = "max of zero initial voltage" -> 0 -> vth 0 -> spike(0>0)=0.
    unsigned v = (i==0) ? 0x80000000u : fmap(-3.0e38f);
    hmaxA[i] = v; omaxA[i] = v;
  }
}

// spike_data [B][I][T] -> XT [T][B][I]
__global__ __launch_bounds__(256) void transpose_kernel(const float* __restrict__ sp,
                                                        float* __restrict__ XT)
{
  __shared__ float tile[64][101];
  int b  = blockIdx.x;
  int i0 = blockIdx.y * 64;
  const float* src = sp + (size_t)b * I_DIM * T_STEPS + (size_t)i0 * T_STEPS;
  for (int e = threadIdx.x; e < 64*T_STEPS; e += 256) {
    int ii = e / T_STEPS, tt = e % T_STEPS;
    tile[ii][tt] = src[(size_t)ii*T_STEPS + tt];
  }
  __syncthreads();
  for (int e = threadIdx.x; e < 64*T_STEPS; e += 256) {
    int tt = e / 64, ii = e % 64;
    XT[((size_t)tt*B_DIM + b)*I_DIM + i0 + ii] = tile[ii][tt];
  }
}

// Fused per-step kernel (1536 blocks):
//   [0,1024):   GEMM1 for step t+1, 64x64 tiles, K-chunk 128 (8 chunks/tile).
//   [1024,1536): GEMM2 for step t,  64x64 tiles, K-chunk 128 (32 chunks/tile).
// Each chunk-block writes its partial tile to its own slice (plain float4 stores),
// fence+ticket; last finisher per tile sums slices, applies the pointwise update,
// and atomicMax'es the next-step dynamic-threshold max. Wait-free (no spinning).
__global__ __launch_bounds__(256, 6) void step_kernel(
    const float* __restrict__ XT,
    const float* __restrict__ Wh,
    const float* __restrict__ Wo,
    const float* __restrict__ hvR,   // hv_t
    float* __restrict__ hvW,         // hv_{t+1}
    float* __restrict__ gp1,         // [NCH1][B][H] partials
    float* __restrict__ gp2,         // [NCH2][B][O] partials
    const float* __restrict__ ovR,   // ov_{t-1}
    float* __restrict__ ovW,         // ov_t (fully written by finishers)
    const unsigned* __restrict__ hmax_t,
    unsigned* __restrict__ hmax_n,
    const unsigned* __restrict__ omax_p,
    unsigned* __restrict__ omax_n,
    unsigned* __restrict__ ticket,
    float* __restrict__ out,
    int t)
{
  const int tid = threadIdx.x;
  const bool g1 = (blockIdx.x < 1024);
  if (g1) { if (t >= T_STEPS-1) return; }
  else    { if (t < 0) return; }

  __shared__ float As[32][68];   // [k][m]
  __shared__ float Bs[32][68];
  __shared__ float red[256];
  __shared__ unsigned sflag;

  const float hvth = vth_of(*hmax_t);

  int mb, nb, kc, tileId, nchunk, ld, ncols;
  const float* Ap; const float* Bp; float* gpart;
  if (g1) {
    int g = blockIdx.x;
    kc = g >> 7; mb = (g >> 6) & 1; nb = g & 63;
    tileId = mb*64 + nb; nchunk = NCH1; ld = I_DIM; ncols = H_DIM;
    Ap = XT + (size_t)(t+1)*B_DIM*I_DIM + (size_t)(mb*64)*I_DIM + kc*128;
    Bp = Wh + (size_t)(nb*64)*I_DIM + kc*128;
    gpart = gp1 + (size_t)kc*B_DIM*H_DIM;
  } else {
    int g = blockIdx.x - 1024;
    kc = g >> 4; mb = (g >> 3) & 1; nb = g & 7;
    tileId = 128 + mb*8 + nb; nchunk = NCH2; ld = H_DIM; ncols = O_DIM;
    Ap = hvR + (size_t)(mb*64)*H_DIM + kc*128;
    Bp = Wo + (size_t)(nb*64)*H_DIM + kc*128;
    gpart = gp2 + (size_t)kc*B_DIM*O_DIM;
  }

  const int lrow = tid >> 2;          // staging row 0..63
  const int lk   = (tid & 3) << 2;    // staging k offset 0,4,8,12
  const float* Arow = Ap + (size_t)lrow*ld + lk;
  const float* Brow = Bp + (size_t)lrow*ld + lk;

  // prefetch stage 0
  float4 a0 = *(const float4*)(Arow);
  float4 a1 = *(const float4*)(Arow + 16);
  float4 b0 = *(const float4*)(Brow);
  float4 b1 = *(const float4*)(Brow + 16);

  const int tx = tid & 15, ty = tid >> 4;
  float acc[4][4];
  #pragma unroll
  for (int r=0;r<4;r++){ acc[r][0]=0.f; acc[r][1]=0.f; acc[r][2]=0.f; acc[r][3]=0.f; }

  for (int s = 0; s < 4; s++) {     // 4 stages of 32 k
    if (!g1) {                      // GEMM2 A operand = spike(hv_t)
      a0.x=(a0.x>hvth)?1.f:0.f; a0.y=(a0.y>hvth)?1.f:0.f;
      a0.z=(a0.z>hvth)?1.f:0.f; a0.w=(a0.w>hvth)?1.f:0.f;
      a1.x=(a1.x>hvth)?1.f:0.f; a1.y=(a1.y>hvth)?1.f:0.f;
      a1.z=(a1.z>hvth)?1.f:0.f; a1.w=(a1.w>hvth)?1.f:0.f;
    }
    __syncthreads();
    As[lk+0 ][lrow]=a0.x; As[lk+1 ][lrow]=a0.y; As[lk+2 ][lrow]=a0.z; As[lk+3 ][lrow]=a0.w;
    As[lk+16][lrow]=a1.x; As[lk+17][lrow]=a1.y; As[lk+18][lrow]=a1.z; As[lk+19][lrow]=a1.w;
    Bs[lk+0 ][lrow]=b0.x; Bs[lk+1 ][lrow]=b0.y; Bs[lk+2 ][lrow]=b0.z; Bs[lk+3 ][lrow]=b0.w;
    Bs[lk+16][lrow]=b1.x; Bs[lk+17][lrow]=b1.y; Bs[lk+18][lrow]=b1.z; Bs[lk+19][lrow]=b1.w;
    __syncthreads();
    if (s < 3) {                    // prefetch next stage: latency hides behind FMAs
      const float* An = Arow + (s+1)*32;
      const float* Bn = Brow + (s+1)*32;
      a0 = *(const float4*)(An); a1 = *(const float4*)(An+16);
      b0 = *(const float4*)(Bn); b1 = *(const float4*)(Bn+16);
    }
    #pragma unroll
    for (int k=0;k<32;k++){
      float4 a = *(const float4*)&As[k][ty<<2];
      float4 b = *(const float4*)&Bs[k][tx<<2];
      acc[0][0] += a.x*b.x; acc[0][1] += a.x*b.y; acc[0][2] += a.x*b.z; acc[0][3] += a.x*b.w;
      acc[1][0] += a.y*b.x; acc[1][1] += a.y*b.y; acc[1][2] += a.y*b.z; acc[1][3] += a.y*b.w;
      acc[2][0] += a.z*b.x; acc[2][1] += a.z*b.y; acc[2][2] += a.z*b.z; acc[2][3] += a.z*b.w;
      acc[3][0] += a.w*b.x; acc[3][1] += a.w*b.y; acc[3][2] += a.w*b.z; acc[3][3] += a.w*b.w;
    }
  }

  const int r0 = mb*64 + (ty<<2);
  const int c0 = nb*64 + (tx<<2);

  if (!g1 && kc==0) {   // exclusive: ov decay/reset base + output-spike accumulation
    float ovth = vth_of(*omax_p);
    #pragma unroll
    for (int r=0;r<4;r++)
      #pragma unroll
      for (int c=0;c<4;c++){
        size_t idx = (size_t)(r0+r)*O_DIM + c0+c;
        float o0 = ovR[idx];
        float os = (o0 > ovth) ? 1.f : 0.f;
        acc[r][c] += 0.5f*o0*(1.f-os);
        out[idx] += os;
      }
  }

  #pragma unroll
  for (int r=0;r<4;r++){
    float4 v = make_float4(acc[r][0],acc[r][1],acc[r][2],acc[r][3]);
    *(float4*)&gpart[(size_t)(r0+r)*ncols + c0] = v;
  }

  __syncthreads();  // all stores issued & drained (compiler waits vmcnt before barrier)
  if (tid==0){ __threadfence(); sflag = atomicAdd(&ticket[tileId], 1u); }
  __syncthreads();
  if (sflag == (unsigned)(nchunk-1)) {    // last finisher of this tile
    __threadfence();                       // acquire: invalidate stale L2 lines
    float lmax = -3.0e38f;
    if (g1) {
      #pragma unroll
      for (int r=0;r<4;r++){
        float sx=0.f, sy=0.f, sz=0.f, sw=0.f;
        #pragma unroll
        for (int q=0;q<NCH1;q++){
          const float4 p = *(const float4*)&gp1[(size_t)q*B_DIM*H_DIM + (size_t)(r0+r)*H_DIM + c0];
          sx+=p.x; sy+=p.y; sz+=p.z; sw+=p.w;
        }
        size_t base = (size_t)(r0+r)*H_DIM + c0;
        float h0,hs,hn;
        h0=hvR[base+0]; hs=(h0>hvth)?1.f:0.f; hn=0.5f*h0*(1.f-hs)+sx; hvW[base+0]=hn; lmax=fmaxf(lmax,hn);
        h0=hvR[base+1]; hs=(h0>hvth)?1.f:0.f; hn=0.5f*h0*(1.f-hs)+sy; hvW[base+1]=hn; lmax=fmaxf(lmax,hn);
        h0=hvR[base+2]; hs=(h0>hvth)?1.f:0.f; hn=0.5f*h0*(1.f-hs)+sz; hvW[base+2]=hn; lmax=fmaxf(lmax,hn);
        h0=hvR[base+3]; hs=(h0>hvth)?1.f:0.f; hn=0.5f*h0*(1.f-hs)+sw; hvW[base+3]=hn; lmax=fmaxf(lmax,hn);
      }
    } else {
      #pragma unroll
      for (int r=0;r<4;r++){
        float sx=0.f, sy=0.f, sz=0.f, sw=0.f;
        for (int q=0;q<NCH2;q++){
          const float4 p = *(const float4*)&gp2[(size_t)q*B_DIM*O_DIM + (size_t)(r0+r)*O_DIM + c0];
          sx+=p.x; sy+=p.y; sz+=p.z; sw+=p.w;
        }
        *(float4*)&ovW[(size_t)(r0+r)*O_DIM + c0] = make_float4(sx,sy,sz,sw);
        lmax = fmaxf(lmax, fmaxf(fmaxf(sx,sy), fmaxf(sz,sw)));
      }
    }
    red[tid]=lmax; __syncthreads();
    for (int sr=128; sr>0; sr>>=1){ if (tid<sr) red[tid]=fmaxf(red[tid],red[tid+sr]); __syncthreads(); }
    if (tid==0){ atomicMax(g1 ? hmax_n : omax_n, fmap(red[0])); ticket[tileId]=0u; }
  }
}

// out += os_{T-1}
__global__ __launch_bounds__(256) void final_kernel(const float* __restrict__ ov,
                                                    const unsigned* __restrict__ omax_last,
                                                    float* __restrict__ out)
{
  int i = blockIdx.x*256 + threadIdx.x;
  if (i < B_DIM*O_DIM) {
    float vth = vth_of(*omax_last);
    out[i] += (ov[i] > vth) ? 1.f : 0.f;
  }
}

extern "C" void kernel_launch(void* const* d_in, const int* in_sizes, int n_in,
                              void* d_out, int out_size, void* d_ws, size_t ws_size,
                              hipStream_t stream) {
  const float* spike = (const float*)d_in[0];
  const float* Wh    = (const float*)d_in[5];   // [H, I]
  const float* Wo    = (const float*)d_in[6];   // [O, H]
  float* out = (float*)d_out;

  char* ws = (char*)d_ws;
  size_t off = 0;
  float* XT = (float*)(ws + off); off += (size_t)T_STEPS*B_DIM*I_DIM*sizeof(float);
  float* hv[2];   hv[0]=(float*)(ws+off); off += (size_t)B_DIM*H_DIM*sizeof(float);
                  hv[1]=(float*)(ws+off); off += (size_t)B_DIM*H_DIM*sizeof(float);
  float* ov[2];   ov[0]=(float*)(ws+off); off += (size_t)B_DIM*O_DIM*sizeof(float);
                  ov[1]=(float*)(ws+off); off += (size_t)B_DIM*O_DIM*sizeof(float);
  float* gp1 = (float*)(ws+off); off += (size_t)NCH1*B_DIM*H_DIM*sizeof(float);
  float* gp2 = (float*)(ws+off); off += (size_t)NCH2*B_DIM*O_DIM*sizeof(float);
  unsigned* hmaxA  = (unsigned*)(ws+off); off += 128*sizeof(unsigned);
  unsigned* omaxA  = (unsigned*)(ws+off); off += 128*sizeof(unsigned);
  unsigned* ticket = (unsigned*)(ws+off); off += 256*sizeof(unsigned);
  (void)ws_size; (void)in_sizes; (void)n_in; (void)out_size;

  init_kernel<<<(B_DIM*H_DIM+255)/256, 256, 0, stream>>>(
      hv[1], ov[1], out, hmaxA, omaxA, ticket);

  transpose_kernel<<<dim3(B_DIM, I_DIM/64), 256, 0, stream>>>(spike, XT);

  for (int t = -1; t < T_STEPS; t++) {
    step_kernel<<<1536, 256, 0, stream>>>(
        XT, Wh, Wo,
        hv[(t+2)&1],        // hv_t
        hv[(t+1)&1],        // hv_{t+1}
        gp1, gp2,
        ov[(t+1)&1],        // ov_{t-1}
        ov[(t+2)&1],        // ov_t
        hmaxA + (t+1), hmaxA + (t+2),
        omaxA + (t < 0 ? 0 : t), omaxA + (t+1),
        ticket, out, t);
  }

  final_kernel<<<(B_DIM*O_DIM+255)/256, 256, 0, stream>>>(ov[1], omaxA + T_STEPS, out);
}

// Round 3
// 5851.765 us; speedup vs baseline: 1.9341x; 1.9341x over previous
//
#include <hip/hip_runtime.h>
#include <math.h>

#define T_STEPS 100
#define B_DIM 128
#define I_DIM 1024
#define H_DIM 4096
#define O_DIM 512
#define T_CHUNK 20   // G buffer covers 20 steps (42MB) to bound workspace

typedef _Float16 f16x8 __attribute__((ext_vector_type(8)));
typedef float    f32x4 __attribute__((ext_vector_type(4)));

// Order-preserving float->uint map so atomicMax(uint) == float max.
__device__ __forceinline__ unsigned fmap(float f){
  unsigned u = __float_as_uint(f);
  return (u & 0x80000000u) ? ~u : (u | 0x80000000u);
}
__device__ __forceinline__ float funmap(unsigned m){
  unsigned u = (m & 0x80000000u) ? (m & 0x7FFFFFFFu) : ~m;
  return __uint_as_float(u);
}
// dyn_vth = vth * tanh(grad_win * max), vth=0.3, grad_win=0.3 (both layers)
__device__ __forceinline__ float vth_of(unsigned m){
  return 0.3f * tanhf(0.3f * funmap(m));
}

__global__ __launch_bounds__(256) void init_kernel(
    float* hv1, float* ov1, float* out,
    unsigned* hmaxA, unsigned* omaxA, unsigned* ticket)
{
  int i = blockIdx.x * 256 + threadIdx.x;
  if (i < B_DIM*H_DIM) hv1[i] = 0.f;
  if (i < B_DIM*O_DIM) { ov1[i] = 0.f; out[i] = 0.f; }
  if (i < 16) ticket[i] = 0u;
  if (i < 128) {
    unsigned v = (i==0) ? 0x80000000u : fmap(-3.0e38f);  // slot0 = max(0)
    hmaxA[i] = v; omaxA[i] = v;
  }
}

// spike_data [B][I][T] fp32 -> fragment-block-tiled f16 hi/lo of (x*2048).
// FB(m16,kc) = 512 f16 at ((m16*32+kc)*512); inside: kg*128 + r*8 + e,
// where m = t*128+b, m16=m/16=t*8+b16, r=b&15, k=i=kc*32+kg*8+e.
__global__ __launch_bounds__(256) void prep_x(const float* __restrict__ sp,
                                              _Float16* __restrict__ Ahi,
                                              _Float16* __restrict__ Alo)
{
  __shared__ float tile[32][16][10];   // [i_local][b_local][t_local]
  const int b16 = blockIdx.x, kc = blockIdx.y, tc = blockIdx.z;
  for (int e = threadIdx.x; e < 5120; e += 256){
    int tt = e % 10, row = e / 10;     // row = bb*32 + ii
    int bb = row >> 5, ii = row & 31;
    tile[ii][bb][tt] =
      sp[((size_t)(b16*16+bb)*I_DIM + kc*32 + ii)*T_STEPS + tc*10 + tt];
  }
  __syncthreads();
  for (int u = threadIdx.x; u < 640; u += 256){
    int tl = u >> 6, l = u & 63, kg = l >> 4, r = l & 15;
    f16x8 hi, lo;
    #pragma unroll
    for (int e=0;e<8;e++){
      float x = tile[kg*8+e][r][tl] * 2048.f;
      _Float16 h = (_Float16)x;
      hi[e] = h;
      lo[e] = (_Float16)(x - (float)h);
    }
    int t = tc*10 + tl;
    size_t off = ((size_t)(t*8 + b16)*32 + kc)*512 + kg*128 + r*8;
    *(f16x8*)(Ahi + off) = hi;
    *(f16x8*)(Alo + off) = lo;
  }
}

// Wh [H][I] fp32 -> FB-tiled f16 hi/lo of (w*256). n16 = h/16, r = h&15.
__global__ __launch_bounds__(256) void prep_w(const float* __restrict__ Wh,
                                              _Float16* __restrict__ Bhi,
                                              _Float16* __restrict__ Blo)
{
  const int n16 = blockIdx.x;   // 0..255
  for (int u = threadIdx.x; u < 2048; u += 256){
    int kc = u >> 6, l = u & 63, kg = l >> 4, r = l & 15;
    const float* src = Wh + (size_t)(n16*16 + r)*I_DIM + kc*32 + kg*8;
    f16x8 hi, lo;
    #pragma unroll
    for (int e=0;e<8;e++){
      float x = src[e] * 256.f;
      _Float16 h = (_Float16)x;
      hi[e] = h;
      lo[e] = (_Float16)(x - (float)h);
    }
    size_t off = ((size_t)n16*32 + kc)*512 + kg*128 + r*8;
    *(f16x8*)(Bhi + off) = hi;
    *(f16x8*)(Blo + off) = lo;
  }
}

// Batched GEMM1: G[m,n] = sum_k A[m,k]*B[n,k] / (2048*256), fp16x3 exact-split MFMA.
// Block = 128x128 C-tile; 4 waves in 2x2; each wave 4x4 subtiles of 16x16x32 MFMA.
// grid: x = bn (0..31), y = bm (0..T_CHUNK-1); block bm handles rows of t = t0+bm.
__global__ __launch_bounds__(256) void gemm1_mfma(
    const _Float16* __restrict__ Ahi, const _Float16* __restrict__ Alo,
    const _Float16* __restrict__ Bhi, const _Float16* __restrict__ Blo,
    float* __restrict__ G, int t0)
{
  __shared__ __align__(16) _Float16 lds[4][8][512];  // [Ahi,Alo,Bhi,Blo][fb][512]
  const int tid = threadIdx.x, wave = tid>>6, lane = tid&63;
  const int bn = blockIdx.x, bm = blockIdx.y;
  const int m16b = (t0+bm)*8, n16b = bn*8;
  const int wm = wave>>1, wn = wave&1;

  const _Float16* srcbase = (wave==0)?Ahi:(wave==1)?Alo:(wave==2)?Bhi:Blo;
  const int r16b = (wave<2) ? m16b : n16b;

  f32x4 acc[16];
  #pragma unroll
  for (int i=0;i<16;i++) acc[i] = (f32x4){0.f,0.f,0.f,0.f};

  int4 rr[8];
  #pragma unroll
  for (int q=0;q<8;q++)
    rr[q] = *(const int4*)(srcbase + ((size_t)(r16b+q)*32)*512 + lane*8);

  for (int kc=0;kc<32;kc++){
    __syncthreads();
    #pragma unroll
    for (int q=0;q<8;q++) *(int4*)&lds[wave][q][lane*8] = rr[q];
    __syncthreads();
    if (kc < 31){
      #pragma unroll
      for (int q=0;q<8;q++)
        rr[q] = *(const int4*)(srcbase + ((size_t)(r16b+q)*32 + kc+1)*512 + lane*8);
    }
    f16x8 fAh[4], fAl[4], fBh[4], fBl[4];
    #pragma unroll
    for (int i=0;i<4;i++){
      fAh[i] = *(const f16x8*)&lds[0][wm*4+i][lane*8];
      fAl[i] = *(const f16x8*)&lds[1][wm*4+i][lane*8];
      fBh[i] = *(const f16x8*)&lds[2][wn*4+i][lane*8];
      fBl[i] = *(const f16x8*)&lds[3][wn*4+i][lane*8];
    }
    #pragma unroll
    for (int i=0;i<4;i++)
      #pragma unroll
      for (int j=0;j<4;j++)
        acc[i*4+j] = __builtin_amdgcn_mfma_f32_16x16x32_f16(fAh[i], fBh[j], acc[i*4+j], 0,0,0);
    #pragma unroll
    for (int i=0;i<4;i++)
      #pragma unroll
      for (int j=0;j<4;j++)
        acc[i*4+j] = __builtin_amdgcn_mfma_f32_16x16x32_f16(fAh[i], fBl[j], acc[i*4+j], 0,0,0);
    #pragma unroll
    for (int i=0;i<4;i++)
      #pragma unroll
      for (int j=0;j<4;j++)
        acc[i*4+j] = __builtin_amdgcn_mfma_f32_16x16x32_f16(fAl[i], fBh[j], acc[i*4+j], 0,0,0);
  }
  const int col = lane&15, quad = lane>>4;
  const float sc = 1.f/(2048.f*256.f);
  #pragma unroll
  for (int i=0;i<4;i++)
    #pragma unroll
    for (int j=0;j<4;j++)
      #pragma unroll
      for (int r=0;r<4;r++){
        int m = bm*128 + wm*64 + i*16 + quad*4 + r;
        int n = bn*128 + wn*64 + j*16 + col;
        G[(size_t)m*H_DIM + n] = acc[i*4+j][r]*sc;
      }
}

// Per-step pointwise: hv_t = 0.5*hv_{t-1}*(1-spike) + G_t; blockmax -> hmax_t.
// Blocks 512..519 zero the ov accumulation target for stepB.
__global__ __launch_bounds__(256) void stepA(
    const float* __restrict__ G, const float* __restrict__ hvR,
    float* __restrict__ hvW, float* __restrict__ ovZ,
    const unsigned* __restrict__ hmax_t, unsigned* __restrict__ hmax_n)
{
  __shared__ float red[256];
  const int tid = threadIdx.x, blk = blockIdx.x;
  if (blk >= 512){
    float4 z = make_float4(0.f,0.f,0.f,0.f);
    int base = (blk-512)*8192 + tid*4;
    #pragma unroll
    for (int q=0;q<8;q++) *(float4*)(ovZ + base + q*1024) = z;
    return;
  }
  const float vth = vth_of(*hmax_t);
  int base = blk*1024 + tid*4;
  float4 g = *(const float4*)(G + base);
  float4 h = *(const float4*)(hvR + base);
  float4 o;
  o.x = (h.x > vth ? 0.f : 0.5f*h.x) + g.x;
  o.y = (h.y > vth ? 0.f : 0.5f*h.y) + g.y;
  o.z = (h.z > vth ? 0.f : 0.5f*h.z) + g.z;
  o.w = (h.w > vth ? 0.f : 0.5f*h.w) + g.w;
  *(float4*)(hvW + base) = o;
  red[tid] = fmaxf(fmaxf(o.x,o.y),fmaxf(o.z,o.w));
  __syncthreads();
  for (int s=128;s>0;s>>=1){ if (tid<s) red[tid]=fmaxf(red[tid],red[tid+s]); __syncthreads(); }
  if (tid==0) atomicMax(hmax_n, fmap(red[0]));
}

// Per-step GEMM2 (R1-proven structure + register prefetch):
// 16 tiles 64x64, K-split 16 chunks of 256 -> 256 blocks. A = spike(hv_t) on the fly.
// atomicAdd partials into ovW; kc==0 adds decay base + accumulates out;
// ticket finisher computes omax_t.
__global__ __launch_bounds__(256) void stepB(
    const float* __restrict__ hv, const float* __restrict__ Wo,
    const float* __restrict__ ovR, float* __restrict__ ovW,
    const unsigned* __restrict__ hmax1,
    const unsigned* __restrict__ omax_p, unsigned* __restrict__ omax_n,
    unsigned* __restrict__ ticket, float* __restrict__ out)
{
  const int tid = threadIdx.x;
  __shared__ float As[32][68], Bs[32][68];
  __shared__ float red[256];
  __shared__ unsigned sflag;
  const int g = blockIdx.x;
  const int kc = g >> 4, mb = (g>>3)&1, nb = g&7, tileId = g&15;
  const float hvth = vth_of(*hmax1);
  const float* Ap = hv + (size_t)(mb*64)*H_DIM + kc*256;
  const float* Bp = Wo + (size_t)(nb*64)*H_DIM + kc*256;
  const int lrow = tid>>2, lk = (tid&3)<<2;
  const float* Arow = Ap + (size_t)lrow*H_DIM + lk;
  const float* Brow = Bp + (size_t)lrow*H_DIM + lk;

  float4 a0 = *(const float4*)(Arow);
  float4 a1 = *(const float4*)(Arow + 16);
  float4 b0 = *(const float4*)(Brow);
  float4 b1 = *(const float4*)(Brow + 16);

  const int tx = tid&15, ty = tid>>4;
  float acc[4][4];
  #pragma unroll
  for (int r=0;r<4;r++){ acc[r][0]=0.f; acc[r][1]=0.f; acc[r][2]=0.f; acc[r][3]=0.f; }

  for (int s=0;s<8;s++){
    a0.x=(a0.x>hvth)?1.f:0.f; a0.y=(a0.y>hvth)?1.f:0.f;
    a0.z=(a0.z>hvth)?1.f:0.f; a0.w=(a0.w>hvth)?1.f:0.f;
    a1.x=(a1.x>hvth)?1.f:0.f; a1.y=(a1.y>hvth)?1.f:0.f;
    a1.z=(a1.z>hvth)?1.f:0.f; a1.w=(a1.w>hvth)?1.f:0.f;
    __syncthreads();
    As[lk+0 ][lrow]=a0.x; As[lk+1 ][lrow]=a0.y; As[lk+2 ][lrow]=a0.z; As[lk+3 ][lrow]=a0.w;
    As[lk+16][lrow]=a1.x; As[lk+17][lrow]=a1.y; As[lk+18][lrow]=a1.z; As[lk+19][lrow]=a1.w;
    Bs[lk+0 ][lrow]=b0.x; Bs[lk+1 ][lrow]=b0.y; Bs[lk+2 ][lrow]=b0.z; Bs[lk+3 ][lrow]=b0.w;
    Bs[lk+16][lrow]=b1.x; Bs[lk+17][lrow]=b1.y; Bs[lk+18][lrow]=b1.z; Bs[lk+19][lrow]=b1.w;
    __syncthreads();
    if (s < 7){
      const float* An = Arow + (s+1)*32;
      const float* Bn = Brow + (s+1)*32;
      a0 = *(const float4*)(An); a1 = *(const float4*)(An+16);
      b0 = *(const float4*)(Bn); b1 = *(const float4*)(Bn+16);
    }
    #pragma unroll
    for (int k=0;k<32;k++){
      float4 a = *(const float4*)&As[k][ty<<2];
      float4 b = *(const float4*)&Bs[k][tx<<2];
      acc[0][0] += a.x*b.x; acc[0][1] += a.x*b.y; acc[0][2] += a.x*b.z; acc[0][3] += a.x*b.w;
      acc[1][0] += a.y*b.x; acc[1][1] += a.y*b.y; acc[1][2] += a.y*b.z; acc[1][3] += a.y*b.w;
      acc[2][0] += a.z*b.x; acc[2][1] += a.z*b.y; acc[2][2] += a.z*b.z; acc[2][3] += a.z*b.w;
      acc[3][0] += a.w*b.x; acc[3][1] += a.w*b.y; acc[3][2] += a.w*b.z; acc[3][3] += a.w*b.w;
    }
  }

  const int r0 = mb*64 + (ty<<2);
  const int c0 = nb*64 + (tx<<2);

  if (kc==0){
    float ovth = vth_of(*omax_p);
    #pragma unroll
    for (int r=0;r<4;r++)
      #pragma unroll
      for (int c=0;c<4;c++){
        size_t idx = (size_t)(r0+r)*O_DIM + c0+c;
        float o0 = ovR[idx];
        float os = (o0 > ovth) ? 1.f : 0.f;
        acc[r][c] += 0.5f*o0*(1.f-os);
        out[idx] += os;
      }
  }
  #pragma unroll
  for (int r=0;r<4;r++)
    #pragma unroll
    for (int c=0;c<4;c++)
      atomicAdd(&ovW[(size_t)(r0+r)*O_DIM + c0+c], acc[r][c]);

  __syncthreads();
  if (tid==0){ __threadfence(); sflag = atomicAdd(&ticket[tileId], 1u); }
  __syncthreads();
  if (sflag == 15u){
    __threadfence();
    float lmax = -3.0e38f;
    #pragma unroll
    for (int r=0;r<4;r++)
      #pragma unroll
      for (int c=0;c<4;c++)
        lmax = fmaxf(lmax, ovW[(size_t)(r0+r)*O_DIM + c0+c]);
    red[tid]=lmax; __syncthreads();
    for (int s=128;s>0;s>>=1){ if (tid<s) red[tid]=fmaxf(red[tid],red[tid+s]); __syncthreads(); }
    if (tid==0){ atomicMax(omax_n, fmap(red[0])); ticket[tileId]=0u; }
  }
}

// out += os_{T-1}
__global__ __launch_bounds__(256) void final_kernel(const float* __restrict__ ov,
                                                    const unsigned* __restrict__ omax_last,
                                                    float* __restrict__ out)
{
  int i = blockIdx.x*256 + threadIdx.x;
  if (i < B_DIM*O_DIM){
    float vth = vth_of(*omax_last);
    out[i] += (ov[i] > vth) ? 1.f : 0.f;
  }
}

extern "C" void kernel_launch(void* const* d_in, const int* in_sizes, int n_in,
                              void* d_out, int out_size, void* d_ws, size_t ws_size,
                              hipStream_t stream) {
  const float* spike = (const float*)d_in[0];
  const float* Wh    = (const float*)d_in[5];   // [H, I]
  const float* Wo    = (const float*)d_in[6];   // [O, H]
  float* out = (float*)d_out;

  char* ws = (char*)d_ws;
  size_t off = 0;
  _Float16* XAhi = (_Float16*)(ws+off); off += (size_t)T_STEPS*B_DIM*I_DIM*2;
  _Float16* XAlo = (_Float16*)(ws+off); off += (size_t)T_STEPS*B_DIM*I_DIM*2;
  _Float16* WHhi = (_Float16*)(ws+off); off += (size_t)H_DIM*I_DIM*2;
  _Float16* WHlo = (_Float16*)(ws+off); off += (size_t)H_DIM*I_DIM*2;
  float* G = (float*)(ws+off);          off += (size_t)T_CHUNK*B_DIM*H_DIM*4;
  float* hv[2]; hv[0]=(float*)(ws+off); off += (size_t)B_DIM*H_DIM*4;
                hv[1]=(float*)(ws+off); off += (size_t)B_DIM*H_DIM*4;
  float* ov[2]; ov[0]=(float*)(ws+off); off += (size_t)B_DIM*O_DIM*4;
                ov[1]=(float*)(ws+off); off += (size_t)B_DIM*O_DIM*4;
  unsigned* hmaxA  = (unsigned*)(ws+off); off += 128*4;
  unsigned* omaxA  = (unsigned*)(ws+off); off += 128*4;
  unsigned* ticket = (unsigned*)(ws+off); off += 64*4;
  (void)ws_size; (void)in_sizes; (void)n_in; (void)out_size;

  init_kernel<<<(B_DIM*H_DIM+255)/256, 256, 0, stream>>>(
      hv[1], ov[1], out, hmaxA, omaxA, ticket);
  prep_x<<<dim3(8,32,10), 256, 0, stream>>>(spike, XAhi, XAlo);
  prep_w<<<256, 256, 0, stream>>>(Wh, WHhi, WHlo);

  for (int c = 0; c < T_STEPS/T_CHUNK; c++){
    gemm1_mfma<<<dim3(32, T_CHUNK), 256, 0, stream>>>(XAhi, XAlo, WHhi, WHlo, G, c*T_CHUNK);
    for (int t = c*T_CHUNK; t < (c+1)*T_CHUNK; t++){
      stepA<<<520, 256, 0, stream>>>(
          G + (size_t)(t - c*T_CHUNK)*B_DIM*H_DIM,
          hv[(t+1)&1], hv[t&1], ov[t&1],
          hmaxA + t, hmaxA + t + 1);
      stepB<<<256, 256, 0, stream>>>(
          hv[t&1], Wo, ov[(t+1)&1], ov[t&1],
          hmaxA + t + 1, omaxA + t, omaxA + t + 1, ticket, out);
    }
  }
  final_kernel<<<(B_DIM*O_DIM+255)/256, 256, 0, stream>>>(ov[1], omaxA + T_STEPS, out);
}